// Round 1
// baseline (881.164 us; speedup 1.0000x reference)
//
#include <hip/hip_runtime.h>

typedef unsigned short u16;
typedef __attribute__((ext_vector_type(8))) short short8;
typedef __attribute__((ext_vector_type(8))) __bf16 bf16x8;
typedef __attribute__((ext_vector_type(4))) float floatx4;

#define BATCH 128
#define SEQ 197
#define CH 768
#define NH 12
#define HD 64
#define MROWS (BATCH * SEQ)   // 25216 = 197 * 128 exactly

__device__ __forceinline__ floatx4 mfma16(short8 a, short8 b, floatx4 c) {
  return __builtin_amdgcn_mfma_f32_16x16x32_bf16(
      __builtin_bit_cast(bf16x8, a), __builtin_bit_cast(bf16x8, b), c, 0, 0, 0);
}

__device__ __forceinline__ u16 f2bf(float f) {
  unsigned u = __builtin_bit_cast(unsigned, f);
  return (u16)((u + 0x7fffu + ((u >> 16) & 1u)) >> 16);
}

// ---------------- fp32 -> bf16 convert (vectorized) ----------------
__global__ __launch_bounds__(256) void cvt_bf16(const float4* __restrict__ in,
                                                ushort4* __restrict__ out, int n4) {
  int i = blockIdx.x * 256 + threadIdx.x;
  if (i < n4) {
    float4 v = in[i];
    ushort4 o;
    o.x = f2bf(v.x); o.y = f2bf(v.y); o.z = f2bf(v.z); o.w = f2bf(v.w);
    out[i] = o;
  }
}

// ---------------- rel position bias gather: relb[h][n][m] ----------------
__global__ __launch_bounds__(256) void gather_relb(const int* __restrict__ idx,
                                                   const float* __restrict__ table,
                                                   float* __restrict__ relb) {
  int t = blockIdx.x * 256 + threadIdx.x;
  if (t < SEQ * SEQ) {
    int id = idx[t];
    const float* row = table + id * NH;
#pragma unroll
    for (int h = 0; h < NH; h++) relb[h * (SEQ * SEQ) + t] = row[h];
  }
}

// ---------------- QKV GEMM: Y = Xbf @ Wbf^T, scatter to q/k/v bufs ----------------
// grid (18, 197), block 256. Block tile 128x128, 4 waves of 64x64.
__global__ __launch_bounds__(256) void gemm_qkv(const u16* __restrict__ A,
                                                const u16* __restrict__ W,
                                                const float* __restrict__ qb,
                                                const float* __restrict__ vb,
                                                u16* __restrict__ q_buf,
                                                u16* __restrict__ k_buf,
                                                u16* __restrict__ v_buf) {
  int tid = threadIdx.x;
  int wave = tid >> 6, lane = tid & 63, quad = lane >> 4, c16 = lane & 15;
  int wm = wave >> 1, wn = wave & 1;
  int m0 = blockIdx.y * 128 + wm * 64;
  int n0 = blockIdx.x * 128 + wn * 64;
  const u16* Ab = A + (size_t)(m0 + c16) * CH + quad * 8;
  const u16* Wb = W + (size_t)(n0 + c16) * CH + quad * 8;
  floatx4 acc[4][4] = {};
#pragma unroll 4
  for (int kk = 0; kk < CH; kk += 32) {
    short8 af[4], bfr[4];
#pragma unroll
    for (int i = 0; i < 4; i++) af[i] = *(const short8*)(Ab + (size_t)i * 16 * CH + kk);
#pragma unroll
    for (int j = 0; j < 4; j++) bfr[j] = *(const short8*)(Wb + (size_t)j * 16 * CH + kk);
#pragma unroll
    for (int i = 0; i < 4; i++)
#pragma unroll
      for (int j = 0; j < 4; j++) acc[i][j] = mfma16(af[i], bfr[j], acc[i][j]);
  }
#pragma unroll
  for (int j = 0; j < 4; j++) {
    int gcol = n0 + j * 16 + c16;        // 0..2303
    int t = gcol / CH;                    // 0=q 1=k 2=v (uniform per tile)
    int rem = gcol - t * CH;              // h*64+d
    int h = rem >> 6, d = rem & 63;
    float badd = (t == 0) ? qb[rem] : (t == 2 ? vb[rem] : 0.0f);
    u16* dst = (t == 0) ? q_buf : (t == 1 ? k_buf : v_buf);
#pragma unroll
    for (int i = 0; i < 4; i++) {
#pragma unroll
      for (int r = 0; r < 4; r++) {
        int grow = m0 + i * 16 + quad * 4 + r;  // 0..25215
        int bb = grow / SEQ;
        int n = grow - bb * SEQ;
        dst[(((size_t)bb * NH + h) * SEQ + n) * HD + d] = f2bf(acc[i][j][r] + badd);
      }
    }
  }
}

// ---------------- attention: one block per (qtile, h, b) ----------------
#define SS 212   // S row stride (floats) -- 212%32=20 breaks softmax read conflicts
#define PS 224   // P row stride (bf16), m padded to 224 (7 k-steps of 32)
#define VS 256   // Vt row stride (bf16), 256 so XOR-swizzle stays in-row

__global__ __launch_bounds__(256) void attn(const u16* __restrict__ q_buf,
                                            const u16* __restrict__ k_buf,
                                            const u16* __restrict__ v_buf,
                                            const float* __restrict__ relb,
                                            u16* __restrict__ attn_out) {
  __shared__ char smem[VS * 64 * 2 + PS * 32 * 2];  // 32768 + 14336 = 47104 B
  float* S = (float*)smem;                    // [32][SS]   (27136 B, dies before Vt)
  u16* Vt = (u16*)smem;                       // [64][VS]   overlaps S (after barrier)
  u16* P = (u16*)(smem + VS * 64 * 2);        // [32][PS]

  int qt = blockIdx.x, h = blockIdx.y, b = blockIdx.z;
  int tid = threadIdx.x, wave = tid >> 6, lane = tid & 63, quad = lane >> 4, c16 = lane & 15;
  size_t bh = (size_t)b * NH + h;
  const u16* Q = q_buf + bh * SEQ * HD;
  const u16* Kp = k_buf + bh * SEQ * HD;
  const u16* Vp = v_buf + bh * SEQ * HD;
  const float* RB = relb + (size_t)h * (SEQ * SEQ);
  int q0 = qt * 32;

  // Phase 1: S = 0.125 * Q K^T + relb   (2x13 tiles of 16x16 over 4 waves)
  for (int tt = wave; tt < 26; tt += 4) {
    int mi = tt / 13, ni = tt - (tt / 13) * 13;
    int qr = min(q0 + mi * 16 + c16, SEQ - 1);   // A-frag row (clamped)
    int mc = min(ni * 16 + c16, SEQ - 1);        // B-frag col = key idx (clamped)
    floatx4 acc = {0.f, 0.f, 0.f, 0.f};
    acc = mfma16(*(const short8*)(Q + qr * HD + quad * 8),
                 *(const short8*)(Kp + mc * HD + quad * 8), acc);
    acc = mfma16(*(const short8*)(Q + qr * HD + 32 + quad * 8),
                 *(const short8*)(Kp + mc * HD + 32 + quad * 8), acc);
    int m = ni * 16 + c16;
#pragma unroll
    for (int r = 0; r < 4; r++) {
      int row = mi * 16 + quad * 4 + r;          // local q row 0..31
      float s = -1e30f;
      if (m < SEQ) s = acc[r] * 0.125f + RB[(size_t)min(q0 + row, SEQ - 1) * SEQ + m];
      S[row * SS + m] = s;
    }
  }
  __syncthreads();

  // Phase 2: softmax (8 lanes per row), write normalized P as bf16 (zero-padded)
  {
    int r = tid >> 3, g = tid & 7;
    float* Sr = S + r * SS;
    float mx = -1e30f;
    for (int m = g; m < SEQ; m += 8) mx = fmaxf(mx, Sr[m]);
    mx = fmaxf(mx, __shfl_xor(mx, 4, 8));
    mx = fmaxf(mx, __shfl_xor(mx, 2, 8));
    mx = fmaxf(mx, __shfl_xor(mx, 1, 8));
    float sum = 0.f;
    for (int m = g; m < SEQ; m += 8) { float e = __expf(Sr[m] - mx); Sr[m] = e; sum += e; }
    sum += __shfl_xor(sum, 4, 8);
    sum += __shfl_xor(sum, 2, 8);
    sum += __shfl_xor(sum, 1, 8);
    float inv = 1.f / sum;
    for (int m = g; m < PS; m += 8)
      P[r * PS + m] = (m < SEQ) ? f2bf(Sr[m] * inv) : (u16)0;
  }
  __syncthreads();

  // Phase 3: transpose V into swizzled Vt[d][m ^ (d&56)]; zero pads. (reuses S space)
  {
    int mrow = tid >> 3, seg = tid & 7, dbase = seg * 8;
#pragma unroll
    for (int i = 0; i < 8; i++) {
      int m = mrow + 32 * i;        // covers 0..255 (full Vt rows)
      int mm = m ^ dbase;           // (dbase+dd)&56 == dbase for dd<8
      if (m < SEQ) {
        ushort4 v0 = *(const ushort4*)(Vp + m * HD + dbase);
        ushort4 v1 = *(const ushort4*)(Vp + m * HD + dbase + 4);
        Vt[(dbase + 0) * VS + mm] = v0.x;
        Vt[(dbase + 1) * VS + mm] = v0.y;
        Vt[(dbase + 2) * VS + mm] = v0.z;
        Vt[(dbase + 3) * VS + mm] = v0.w;
        Vt[(dbase + 4) * VS + mm] = v1.x;
        Vt[(dbase + 5) * VS + mm] = v1.y;
        Vt[(dbase + 6) * VS + mm] = v1.z;
        Vt[(dbase + 7) * VS + mm] = v1.w;
      } else {
#pragma unroll
        for (int dd = 0; dd < 8; dd++) Vt[(dbase + dd) * VS + mm] = 0;
      }
    }
  }
  __syncthreads();

  // Phase 4: O = P @ V   (2x4 tiles over 4 waves, 7 k-steps of 32)
  for (int tt = wave; tt < 8; tt += 4) {
    int mi = tt >> 2, ni = tt & 3;
    const u16* Pr = P + (mi * 16 + c16) * PS;
    int d = ni * 16 + c16;
    const u16* Vr = Vt + d * VS;
    int sw = d & 56;
    floatx4 acc = {0.f, 0.f, 0.f, 0.f};
#pragma unroll
    for (int ks = 0; ks < 7; ks++) {
      short8 a = *(const short8*)(Pr + ks * 32 + quad * 8);
      short8 bb = *(const short8*)(Vr + ((ks * 32 + quad * 8) ^ sw));
      acc = mfma16(a, bb, acc);
    }
#pragma unroll
    for (int r = 0; r < 4; r++) {
      int grow = q0 + mi * 16 + quad * 4 + r;
      if (grow < SEQ)
        attn_out[((size_t)b * SEQ + grow) * CH + h * HD + d] = f2bf(acc[r]);
    }
  }
}

// ---------------- proj GEMM: out = AO @ Wp^T + b (fp32 out) ----------------
__global__ __launch_bounds__(256) void gemm_proj(const u16* __restrict__ A,
                                                 const u16* __restrict__ W,
                                                 const float* __restrict__ bias,
                                                 float* __restrict__ out) {
  int tid = threadIdx.x;
  int wave = tid >> 6, lane = tid & 63, quad = lane >> 4, c16 = lane & 15;
  int wm = wave >> 1, wn = wave & 1;
  int m0 = blockIdx.y * 128 + wm * 64;
  int n0 = blockIdx.x * 128 + wn * 64;
  const u16* Ab = A + (size_t)(m0 + c16) * CH + quad * 8;
  const u16* Wb = W + (size_t)(n0 + c16) * CH + quad * 8;
  floatx4 acc[4][4] = {};
#pragma unroll 4
  for (int kk = 0; kk < CH; kk += 32) {
    short8 af[4], bfr[4];
#pragma unroll
    for (int i = 0; i < 4; i++) af[i] = *(const short8*)(Ab + (size_t)i * 16 * CH + kk);
#pragma unroll
    for (int j = 0; j < 4; j++) bfr[j] = *(const short8*)(Wb + (size_t)j * 16 * CH + kk);
#pragma unroll
    for (int i = 0; i < 4; i++)
#pragma unroll
      for (int j = 0; j < 4; j++) acc[i][j] = mfma16(af[i], bfr[j], acc[i][j]);
  }
#pragma unroll
  for (int j = 0; j < 4; j++) {
    int gcol = n0 + j * 16 + c16;
    float bj = bias[gcol];
#pragma unroll
    for (int i = 0; i < 4; i++)
#pragma unroll
      for (int r = 0; r < 4; r++) {
        int grow = m0 + i * 16 + quad * 4 + r;
        out[(size_t)grow * CH + gcol] = acc[i][j][r] + bj;
      }
  }
}

extern "C" void kernel_launch(void* const* d_in, const int* in_sizes, int n_in,
                              void* d_out, int out_size, void* d_ws, size_t ws_size,
                              hipStream_t stream) {
  const float* x      = (const float*)d_in[0];
  const float* qkv_w  = (const float*)d_in[1];
  const float* q_bias = (const float*)d_in[2];
  const float* v_bias = (const float*)d_in[3];
  const float* table  = (const float*)d_in[4];
  const float* proj_w = (const float*)d_in[5];
  const float* proj_b = (const float*)d_in[6];
  const int*   rel_ix = (const int*)d_in[7];
  float* out = (float*)d_out;

  char* ws = (char*)d_ws;
  size_t off = 0;
  u16* x_bf  = (u16*)(ws + off); off += (size_t)MROWS * CH * 2;       // 38.7 MB
  u16* wq_bf = (u16*)(ws + off); off += (size_t)3 * CH * CH * 2;      // 3.5 MB
  u16* wp_bf = (u16*)(ws + off); off += (size_t)CH * CH * 2;          // 1.2 MB
  u16* q_buf = (u16*)(ws + off); off += (size_t)MROWS * CH * 2;       // 38.7 MB
  u16* k_buf = (u16*)(ws + off); off += (size_t)MROWS * CH * 2;       // 38.7 MB
  u16* v_buf = (u16*)(ws + off); off += (size_t)MROWS * CH * 2;       // 38.7 MB
  u16* ao_bf = (u16*)(ws + off); off += (size_t)MROWS * CH * 2;       // 38.7 MB
  float* relb = (float*)(ws + off);                                    // 1.9 MB

  int n4x = MROWS * CH / 4;
  int n4q = 3 * CH * CH / 4;
  int n4p = CH * CH / 4;
  cvt_bf16<<<(n4x + 255) / 256, 256, 0, stream>>>((const float4*)x, (ushort4*)x_bf, n4x);
  cvt_bf16<<<(n4q + 255) / 256, 256, 0, stream>>>((const float4*)qkv_w, (ushort4*)wq_bf, n4q);
  cvt_bf16<<<(n4p + 255) / 256, 256, 0, stream>>>((const float4*)proj_w, (ushort4*)wp_bf, n4p);
  gather_relb<<<(SEQ * SEQ + 255) / 256, 256, 0, stream>>>(rel_ix, table, relb);
  gemm_qkv<<<dim3(18, 197), 256, 0, stream>>>(x_bf, wq_bf, q_bias, v_bias, q_buf, k_buf, v_buf);
  attn<<<dim3(7, NH, BATCH), 256, 0, stream>>>(q_buf, k_buf, v_buf, relb, ao_bf);
  gemm_proj<<<dim3(6, 197), 256, 0, stream>>>(ao_bf, wp_bf, proj_b, out);
}

// Round 2
// 649.067 us; speedup vs baseline: 1.3576x; 1.3576x over previous
//
#include <hip/hip_runtime.h>

typedef unsigned short u16;
typedef __attribute__((ext_vector_type(8))) short short8;
typedef __attribute__((ext_vector_type(8))) __bf16 bf16x8;
typedef __attribute__((ext_vector_type(4))) float floatx4;

#define BATCH 128
#define SEQ 197
#define CH 768
#define NH 12
#define HD 64
#define MROWS (BATCH * SEQ)   // 25216 = 197 * 128 exactly

__device__ __forceinline__ floatx4 mfma16(short8 a, short8 b, floatx4 c) {
  return __builtin_amdgcn_mfma_f32_16x16x32_bf16(
      __builtin_bit_cast(bf16x8, a), __builtin_bit_cast(bf16x8, b), c, 0, 0, 0);
}

__device__ __forceinline__ u16 f2bf(float f) {
  unsigned u = __builtin_bit_cast(unsigned, f);
  return (u16)((u + 0x7fffu + ((u >> 16) & 1u)) >> 16);
}

// async global->LDS, 16B per lane; LDS dest must be wave-uniform base (HW adds lane*16)
__device__ __forceinline__ void async16(const u16* g, u16* s) {
  __builtin_amdgcn_global_load_lds((const __attribute__((address_space(1))) void*)g,
                                   (__attribute__((address_space(3))) void*)s, 16, 0, 0);
}

// ---------------- fp32 -> bf16 convert (vectorized) ----------------
__global__ __launch_bounds__(256) void cvt_bf16(const float4* __restrict__ in,
                                                ushort4* __restrict__ out, int n4) {
  int i = blockIdx.x * 256 + threadIdx.x;
  if (i < n4) {
    float4 v = in[i];
    ushort4 o;
    o.x = f2bf(v.x); o.y = f2bf(v.y); o.z = f2bf(v.z); o.w = f2bf(v.w);
    out[i] = o;
  }
}

// ---------------- rel position bias gather: relb[h][n][m] ----------------
__global__ __launch_bounds__(256) void gather_relb(const int* __restrict__ idx,
                                                   const float* __restrict__ table,
                                                   float* __restrict__ relb) {
  int t = blockIdx.x * 256 + threadIdx.x;
  if (t < SEQ * SEQ) {
    int id = idx[t];
    const float* row = table + id * NH;
#pragma unroll
    for (int h = 0; h < NH; h++) relb[h * (SEQ * SEQ) + t] = row[h];
  }
}

// ---------------- QKV GEMM: LDS-staged (m97 structure), scatter epilogue ----------------
// grid (18, 197), block 256 = 4 waves, block tile 128x128, BK=32.
__global__ __launch_bounds__(256) void gemm_qkv(const u16* __restrict__ A,
                                                const u16* __restrict__ W,
                                                const float* __restrict__ qb,
                                                const float* __restrict__ vb,
                                                u16* __restrict__ q_buf,
                                                u16* __restrict__ k_buf,
                                                u16* __restrict__ v_buf) {
  __shared__ u16 As[128 * 32];
  __shared__ u16 Bs[128 * 32];
  int tid = threadIdx.x;
  int wave = tid >> 6, lane = tid & 63, quad = lane >> 4, c16 = lane & 15;
  int wm = wave >> 1, wn = wave & 1;
  int m0 = blockIdx.y * 128, n0 = blockIdx.x * 128;
  // staging: wave stages 32 rows of A and 32 rows of B (two 16-row chunks each)
  const u16* Ag = A + (size_t)(m0 + wave * 32 + (lane >> 2)) * CH + (lane & 3) * 8;
  const u16* Wg = W + (size_t)(n0 + wave * 32 + (lane >> 2)) * CH + (lane & 3) * 8;
  u16* AsW = As + wave * 32 * 32;
  u16* BsW = Bs + wave * 32 * 32;
  // fragment read bases (constant across k-steps)
  const u16* ArF = As + (wm * 64 + c16) * 32 + quad * 8;
  const u16* BrF = Bs + (wn * 64 + c16) * 32 + quad * 8;
  floatx4 acc[4][4] = {};
  for (int kk = 0; kk < CH; kk += 32) {
    __syncthreads();
    async16(Ag + kk, AsW);
    async16(Ag + kk + (size_t)16 * CH, AsW + 16 * 32);
    async16(Wg + kk, BsW);
    async16(Wg + kk + (size_t)16 * CH, BsW + 16 * 32);
    __syncthreads();   // drains vmcnt (global_load_lds) per barrier semantics
    short8 af[4], bfr[4];
#pragma unroll
    for (int i = 0; i < 4; i++) af[i] = *(const short8*)(ArF + i * 16 * 32);
#pragma unroll
    for (int j = 0; j < 4; j++) bfr[j] = *(const short8*)(BrF + j * 16 * 32);
#pragma unroll
    for (int i = 0; i < 4; i++)
#pragma unroll
      for (int j = 0; j < 4; j++) acc[i][j] = mfma16(af[i], bfr[j], acc[i][j]);
  }
#pragma unroll
  for (int j = 0; j < 4; j++) {
    int gcol = n0 + wn * 64 + j * 16 + c16;  // 0..2303
    int t = gcol / CH;                        // 0=q 1=k 2=v (uniform per 16-col group)
    int rem = gcol - t * CH;                  // h*64+d
    int h = rem >> 6, d = rem & 63;
    float badd = (t == 0) ? qb[rem] : (t == 2 ? vb[rem] : 0.0f);
    u16* dst = (t == 0) ? q_buf : (t == 1 ? k_buf : v_buf);
#pragma unroll
    for (int i = 0; i < 4; i++) {
#pragma unroll
      for (int r = 0; r < 4; r++) {
        int grow = m0 + wm * 64 + i * 16 + quad * 4 + r;  // 0..25215
        int bb = grow / SEQ;
        int n = grow - bb * SEQ;
        dst[(((size_t)bb * NH + h) * SEQ + n) * HD + d] = f2bf(acc[i][j][r] + badd);
      }
    }
  }
}

// ---------------- attention: one block per (qtile, h, b) ----------------
#define SS 212   // S row stride (floats)
#define PS 224   // P row stride (bf16), m padded to 224 (7 k-steps of 32)
#define VS 256   // Vt row stride (bf16), 256 so XOR-swizzle stays in-row

__global__ __launch_bounds__(256) void attn(const u16* __restrict__ q_buf,
                                            const u16* __restrict__ k_buf,
                                            const u16* __restrict__ v_buf,
                                            const float* __restrict__ relb,
                                            u16* __restrict__ attn_out) {
  __shared__ char smem[VS * 64 * 2 + PS * 32 * 2];  // 32768 + 14336 = 47104 B
  float* S = (float*)smem;                    // [32][SS]   (dies before Vt)
  u16* Vt = (u16*)smem;                       // [64][VS]   overlaps S (after barrier)
  u16* P = (u16*)(smem + VS * 64 * 2);        // [32][PS]

  int qt = blockIdx.x, h = blockIdx.y, b = blockIdx.z;
  int tid = threadIdx.x, wave = tid >> 6, lane = tid & 63, quad = lane >> 4, c16 = lane & 15;
  size_t bh = (size_t)b * NH + h;
  const u16* Q = q_buf + bh * SEQ * HD;
  const u16* Kp = k_buf + bh * SEQ * HD;
  const u16* Vp = v_buf + bh * SEQ * HD;
  const float* RB = relb + (size_t)h * (SEQ * SEQ);
  int q0 = qt * 32;

  // Phase 1: S = 0.125 * Q K^T + relb
  for (int tt = wave; tt < 26; tt += 4) {
    int mi = tt / 13, ni = tt - (tt / 13) * 13;
    int qr = min(q0 + mi * 16 + c16, SEQ - 1);
    int mc = min(ni * 16 + c16, SEQ - 1);
    floatx4 acc = {0.f, 0.f, 0.f, 0.f};
    acc = mfma16(*(const short8*)(Q + qr * HD + quad * 8),
                 *(const short8*)(Kp + mc * HD + quad * 8), acc);
    acc = mfma16(*(const short8*)(Q + qr * HD + 32 + quad * 8),
                 *(const short8*)(Kp + mc * HD + 32 + quad * 8), acc);
    int m = ni * 16 + c16;
#pragma unroll
    for (int r = 0; r < 4; r++) {
      int row = mi * 16 + quad * 4 + r;
      float s = -1e30f;
      if (m < SEQ) s = acc[r] * 0.125f + RB[(size_t)min(q0 + row, SEQ - 1) * SEQ + m];
      S[row * SS + m] = s;
    }
  }
  __syncthreads();

  // Phase 2: softmax (8 lanes per row), write normalized P as bf16 (zero-padded)
  {
    int r = tid >> 3, g = tid & 7;
    float* Sr = S + r * SS;
    float mx = -1e30f;
    for (int m = g; m < SEQ; m += 8) mx = fmaxf(mx, Sr[m]);
    mx = fmaxf(mx, __shfl_xor(mx, 4, 8));
    mx = fmaxf(mx, __shfl_xor(mx, 2, 8));
    mx = fmaxf(mx, __shfl_xor(mx, 1, 8));
    float sum = 0.f;
    for (int m = g; m < SEQ; m += 8) { float e = __expf(Sr[m] - mx); Sr[m] = e; sum += e; }
    sum += __shfl_xor(sum, 4, 8);
    sum += __shfl_xor(sum, 2, 8);
    sum += __shfl_xor(sum, 1, 8);
    float inv = 1.f / sum;
    for (int m = g; m < PS; m += 8)
      P[r * PS + m] = (m < SEQ) ? f2bf(Sr[m] * inv) : (u16)0;
  }
  __syncthreads();

  // Phase 3: transpose V into swizzled Vt[d][m ^ (d&56)]; zero pads
  {
    int mrow = tid >> 3, seg = tid & 7, dbase = seg * 8;
#pragma unroll
    for (int i = 0; i < 8; i++) {
      int m = mrow + 32 * i;
      int mm = m ^ dbase;
      if (m < SEQ) {
        ushort4 v0 = *(const ushort4*)(Vp + m * HD + dbase);
        ushort4 v1 = *(const ushort4*)(Vp + m * HD + dbase + 4);
        Vt[(dbase + 0) * VS + mm] = v0.x;
        Vt[(dbase + 1) * VS + mm] = v0.y;
        Vt[(dbase + 2) * VS + mm] = v0.z;
        Vt[(dbase + 3) * VS + mm] = v0.w;
        Vt[(dbase + 4) * VS + mm] = v1.x;
        Vt[(dbase + 5) * VS + mm] = v1.y;
        Vt[(dbase + 6) * VS + mm] = v1.z;
        Vt[(dbase + 7) * VS + mm] = v1.w;
      } else {
#pragma unroll
        for (int dd = 0; dd < 8; dd++) Vt[(dbase + dd) * VS + mm] = 0;
      }
    }
  }
  __syncthreads();

  // Phase 4: O = P @ V
  for (int tt = wave; tt < 8; tt += 4) {
    int mi = tt >> 2, ni = tt & 3;
    const u16* Pr = P + (mi * 16 + c16) * PS;
    int d = ni * 16 + c16;
    const u16* Vr = Vt + d * VS;
    int sw = d & 56;
    floatx4 acc = {0.f, 0.f, 0.f, 0.f};
#pragma unroll
    for (int ks = 0; ks < 7; ks++) {
      short8 a = *(const short8*)(Pr + ks * 32 + quad * 8);
      short8 bb = *(const short8*)(Vr + ((ks * 32 + quad * 8) ^ sw));
      acc = mfma16(a, bb, acc);
    }
#pragma unroll
    for (int r = 0; r < 4; r++) {
      int grow = q0 + mi * 16 + quad * 4 + r;
      if (grow < SEQ)
        attn_out[((size_t)b * SEQ + grow) * CH + h * HD + d] = f2bf(acc[r]);
    }
  }
}

// ---------------- proj GEMM: LDS-staged, out = AO @ Wp^T + b (fp32 out) ----------------
__global__ __launch_bounds__(256) void gemm_proj(const u16* __restrict__ A,
                                                 const u16* __restrict__ W,
                                                 const float* __restrict__ bias,
                                                 float* __restrict__ out) {
  __shared__ u16 As[128 * 32];
  __shared__ u16 Bs[128 * 32];
  int tid = threadIdx.x;
  int wave = tid >> 6, lane = tid & 63, quad = lane >> 4, c16 = lane & 15;
  int wm = wave >> 1, wn = wave & 1;
  int m0 = blockIdx.y * 128, n0 = blockIdx.x * 128;
  const u16* Ag = A + (size_t)(m0 + wave * 32 + (lane >> 2)) * CH + (lane & 3) * 8;
  const u16* Wg = W + (size_t)(n0 + wave * 32 + (lane >> 2)) * CH + (lane & 3) * 8;
  u16* AsW = As + wave * 32 * 32;
  u16* BsW = Bs + wave * 32 * 32;
  const u16* ArF = As + (wm * 64 + c16) * 32 + quad * 8;
  const u16* BrF = Bs + (wn * 64 + c16) * 32 + quad * 8;
  floatx4 acc[4][4] = {};
  for (int kk = 0; kk < CH; kk += 32) {
    __syncthreads();
    async16(Ag + kk, AsW);
    async16(Ag + kk + (size_t)16 * CH, AsW + 16 * 32);
    async16(Wg + kk, BsW);
    async16(Wg + kk + (size_t)16 * CH, BsW + 16 * 32);
    __syncthreads();
    short8 af[4], bfr[4];
#pragma unroll
    for (int i = 0; i < 4; i++) af[i] = *(const short8*)(ArF + i * 16 * 32);
#pragma unroll
    for (int j = 0; j < 4; j++) bfr[j] = *(const short8*)(BrF + j * 16 * 32);
#pragma unroll
    for (int i = 0; i < 4; i++)
#pragma unroll
      for (int j = 0; j < 4; j++) acc[i][j] = mfma16(af[i], bfr[j], acc[i][j]);
  }
#pragma unroll
  for (int j = 0; j < 4; j++) {
    int gcol = n0 + wn * 64 + j * 16 + c16;
    float bj = bias[gcol];
#pragma unroll
    for (int i = 0; i < 4; i++)
#pragma unroll
      for (int r = 0; r < 4; r++) {
        int grow = m0 + wm * 64 + i * 16 + quad * 4 + r;
        out[(size_t)grow * CH + gcol] = acc[i][j][r] + bj;
      }
  }
}

extern "C" void kernel_launch(void* const* d_in, const int* in_sizes, int n_in,
                              void* d_out, int out_size, void* d_ws, size_t ws_size,
                              hipStream_t stream) {
  const float* x      = (const float*)d_in[0];
  const float* qkv_w  = (const float*)d_in[1];
  const float* q_bias = (const float*)d_in[2];
  const float* v_bias = (const float*)d_in[3];
  const float* table  = (const float*)d_in[4];
  const float* proj_w = (const float*)d_in[5];
  const float* proj_b = (const float*)d_in[6];
  const int*   rel_ix = (const int*)d_in[7];
  float* out = (float*)d_out;

  char* ws = (char*)d_ws;
  size_t off = 0;
  u16* x_bf  = (u16*)(ws + off); off += (size_t)MROWS * CH * 2;
  u16* wq_bf = (u16*)(ws + off); off += (size_t)3 * CH * CH * 2;
  u16* wp_bf = (u16*)(ws + off); off += (size_t)CH * CH * 2;
  u16* q_buf = (u16*)(ws + off); off += (size_t)MROWS * CH * 2;
  u16* k_buf = (u16*)(ws + off); off += (size_t)MROWS * CH * 2;
  u16* v_buf = (u16*)(ws + off); off += (size_t)MROWS * CH * 2;
  u16* ao_bf = (u16*)(ws + off); off += (size_t)MROWS * CH * 2;
  float* relb = (float*)(ws + off);

  int n4x = MROWS * CH / 4;
  int n4q = 3 * CH * CH / 4;
  int n4p = CH * CH / 4;
  cvt_bf16<<<(n4x + 255) / 256, 256, 0, stream>>>((const float4*)x, (ushort4*)x_bf, n4x);
  cvt_bf16<<<(n4q + 255) / 256, 256, 0, stream>>>((const float4*)qkv_w, (ushort4*)wq_bf, n4q);
  cvt_bf16<<<(n4p + 255) / 256, 256, 0, stream>>>((const float4*)proj_w, (ushort4*)wp_bf, n4p);
  gather_relb<<<(SEQ * SEQ + 255) / 256, 256, 0, stream>>>(rel_ix, table, relb);
  gemm_qkv<<<dim3(18, 197), 256, 0, stream>>>(x_bf, wq_bf, q_bias, v_bias, q_buf, k_buf, v_buf);
  attn<<<dim3(7, NH, BATCH), 256, 0, stream>>>(q_buf, k_buf, v_buf, relb, ao_bf);
  gemm_proj<<<dim3(6, 197), 256, 0, stream>>>(ao_bf, wp_bf, proj_b, out);
}

// Round 3
// 441.509 us; speedup vs baseline: 1.9958x; 1.4701x over previous
//
#include <hip/hip_runtime.h>

typedef unsigned short u16;
typedef __attribute__((ext_vector_type(8))) short short8;
typedef __attribute__((ext_vector_type(8))) __bf16 bf16x8;
typedef __attribute__((ext_vector_type(4))) float floatx4;

#define BATCH 128
#define SEQ 197
#define CH 768
#define NH 12
#define HD 64
#define MROWS (BATCH * SEQ)   // 25216 = 197 * 128 exactly

__device__ __forceinline__ floatx4 mfma16(short8 a, short8 b, floatx4 c) {
  return __builtin_amdgcn_mfma_f32_16x16x32_bf16(
      __builtin_bit_cast(bf16x8, a), __builtin_bit_cast(bf16x8, b), c, 0, 0, 0);
}

__device__ __forceinline__ u16 f2bf(float f) {
  unsigned u = __builtin_bit_cast(unsigned, f);
  return (u16)((u + 0x7fffu + ((u >> 16) & 1u)) >> 16);
}

// async global->LDS, 16B per lane; LDS dest must be wave-uniform base (HW adds lane*16)
__device__ __forceinline__ void async16(const u16* g, u16* s) {
  __builtin_amdgcn_global_load_lds((const __attribute__((address_space(1))) void*)g,
                                   (__attribute__((address_space(3))) void*)s, 16, 0, 0);
}

// ---------------- fp32 -> bf16 convert (vectorized) ----------------
__global__ __launch_bounds__(256) void cvt_bf16(const float4* __restrict__ in,
                                                ushort4* __restrict__ out, int n4) {
  int i = blockIdx.x * 256 + threadIdx.x;
  if (i < n4) {
    float4 v = in[i];
    ushort4 o;
    o.x = f2bf(v.x); o.y = f2bf(v.y); o.z = f2bf(v.z); o.w = f2bf(v.w);
    out[i] = o;
  }
}

// ---------------- rel position bias gather: relb[h][n][m] ----------------
__global__ __launch_bounds__(256) void gather_relb(const int* __restrict__ idx,
                                                   const float* __restrict__ table,
                                                   float* __restrict__ relb) {
  int t = blockIdx.x * 256 + threadIdx.x;
  if (t < SEQ * SEQ) {
    int id = idx[t];
    const float* row = table + id * NH;
#pragma unroll
    for (int h = 0; h < NH; h++) relb[h * (SEQ * SEQ) + t] = row[h];
  }
}

// ---------------- QKV GEMM: LDS-staged (m97 structure), scatter epilogue ----------------
__global__ __launch_bounds__(256) void gemm_qkv(const u16* __restrict__ A,
                                                const u16* __restrict__ W,
                                                const float* __restrict__ qb,
                                                const float* __restrict__ vb,
                                                u16* __restrict__ q_buf,
                                                u16* __restrict__ k_buf,
                                                u16* __restrict__ v_buf) {
  __shared__ u16 As[128 * 32];
  __shared__ u16 Bs[128 * 32];
  int tid = threadIdx.x;
  int wave = tid >> 6, lane = tid & 63, quad = lane >> 4, c16 = lane & 15;
  int wm = wave >> 1, wn = wave & 1;
  int m0 = blockIdx.y * 128, n0 = blockIdx.x * 128;
  const u16* Ag = A + (size_t)(m0 + wave * 32 + (lane >> 2)) * CH + (lane & 3) * 8;
  const u16* Wg = W + (size_t)(n0 + wave * 32 + (lane >> 2)) * CH + (lane & 3) * 8;
  u16* AsW = As + wave * 32 * 32;
  u16* BsW = Bs + wave * 32 * 32;
  const u16* ArF = As + (wm * 64 + c16) * 32 + quad * 8;
  const u16* BrF = Bs + (wn * 64 + c16) * 32 + quad * 8;
  floatx4 acc[4][4] = {};
  for (int kk = 0; kk < CH; kk += 32) {
    __syncthreads();
    async16(Ag + kk, AsW);
    async16(Ag + kk + (size_t)16 * CH, AsW + 16 * 32);
    async16(Wg + kk, BsW);
    async16(Wg + kk + (size_t)16 * CH, BsW + 16 * 32);
    __syncthreads();
    short8 af[4], bfr[4];
#pragma unroll
    for (int i = 0; i < 4; i++) af[i] = *(const short8*)(ArF + i * 16 * 32);
#pragma unroll
    for (int j = 0; j < 4; j++) bfr[j] = *(const short8*)(BrF + j * 16 * 32);
#pragma unroll
    for (int i = 0; i < 4; i++)
#pragma unroll
      for (int j = 0; j < 4; j++) acc[i][j] = mfma16(af[i], bfr[j], acc[i][j]);
  }
#pragma unroll
  for (int j = 0; j < 4; j++) {
    int gcol = n0 + wn * 64 + j * 16 + c16;
    int t = gcol / CH;
    int rem = gcol - t * CH;
    int h = rem >> 6, d = rem & 63;
    float badd = (t == 0) ? qb[rem] : (t == 2 ? vb[rem] : 0.0f);
    u16* dst = (t == 0) ? q_buf : (t == 1 ? k_buf : v_buf);
#pragma unroll
    for (int i = 0; i < 4; i++) {
#pragma unroll
      for (int r = 0; r < 4; r++) {
        int grow = m0 + wm * 64 + i * 16 + quad * 4 + r;
        int bb = grow / SEQ;
        int n = grow - bb * SEQ;
        dst[(((size_t)bb * NH + h) * SEQ + n) * HD + d] = f2bf(acc[i][j][r] + badd);
      }
    }
  }
}

// ---------------- attention v3: one block per (h, b), register softmax ----------------
// PS=232 u16: row stride 116 words -> bank shift 20/row, all 16 rows distinct groups.
// VS=264 u16: row stride 132 words -> bank shift 4/row, 8 distinct groups (2-way free).
#define PS 232
#define VS 264

__global__ __launch_bounds__(256, 2) void attn(const u16* __restrict__ q_buf,
                                               const u16* __restrict__ k_buf,
                                               const u16* __restrict__ v_buf,
                                               const float* __restrict__ relb,
                                               u16* __restrict__ attn_out) {
  __shared__ u16 Vt[64 * VS];        // 33792 B : V transposed [d][m], zero-padded m>=197
  __shared__ u16 P[4 * 16 * PS];     // 29696 B : per-wave P tiles

  int h = blockIdx.x, b = blockIdx.y;
  int tid = threadIdx.x, wave = tid >> 6, lane = tid & 63, quad = lane >> 4, c16 = lane & 15;
  size_t bh = (size_t)b * NH + h;
  const u16* Q = q_buf + bh * SEQ * HD;
  const u16* Kp = k_buf + bh * SEQ * HD;
  const u16* Vp = v_buf + bh * SEQ * HD;
  const float* RB = relb + (size_t)h * (SEQ * SEQ);

  // Build Vt once per block: thread (mrow=tid>>3, seg=tid&7) handles d in [seg*8, seg*8+8)
  {
    int mrow = tid >> 3, dbase = (tid & 7) * 8;
#pragma unroll
    for (int i = 0; i < 7; i++) {
      int m = mrow + 32 * i;                  // 0..223 (all k-loop-visible columns)
      if (m < SEQ) {
        ushort4 v0 = *(const ushort4*)(Vp + m * HD + dbase);
        ushort4 v1 = *(const ushort4*)(Vp + m * HD + dbase + 4);
        Vt[(dbase + 0) * VS + m] = v0.x;
        Vt[(dbase + 1) * VS + m] = v0.y;
        Vt[(dbase + 2) * VS + m] = v0.z;
        Vt[(dbase + 3) * VS + m] = v0.w;
        Vt[(dbase + 4) * VS + m] = v1.x;
        Vt[(dbase + 5) * VS + m] = v1.y;
        Vt[(dbase + 6) * VS + m] = v1.z;
        Vt[(dbase + 7) * VS + m] = v1.w;
      } else {
#pragma unroll
        for (int dd = 0; dd < 8; dd++) Vt[(dbase + dd) * VS + m] = 0;
      }
    }
  }
  __syncthreads();   // the only barrier

  u16* Pw = P + wave * 16 * PS;
  for (int rt = wave; rt < 13; rt += 4) {
    int q0 = rt * 16;
    // Q A-fragments for this 16-row tile (clamped rows; garbage rows masked at write)
    int qr = min(q0 + c16, SEQ - 1);
    short8 qa0 = *(const short8*)(Q + qr * HD + quad * 8);
    short8 qa1 = *(const short8*)(Q + qr * HD + 32 + quad * 8);

    // S = Q K^T over all 13 n-tiles, held in registers (C-layout)
    floatx4 sacc[13];
#pragma unroll
    for (int nt = 0; nt < 13; nt++) {
      int mc = min(nt * 16 + c16, SEQ - 1);
      floatx4 a = {0.f, 0.f, 0.f, 0.f};
      a = mfma16(qa0, *(const short8*)(Kp + mc * HD + quad * 8), a);
      a = mfma16(qa1, *(const short8*)(Kp + mc * HD + 32 + quad * 8), a);
      sacc[nt] = a;
    }

    // bias + mask + softmax, entirely in registers (row = quad*4+r, col = c16)
#pragma unroll
    for (int r = 0; r < 4; r++) {
      int rq = min(q0 + quad * 4 + r, SEQ - 1);
      const float* RBr = RB + (size_t)rq * SEQ;
      float mx = -1e30f;
#pragma unroll
      for (int nt = 0; nt < 13; nt++) {
        int m = nt * 16 + c16;
        float s = -1e30f;
        if (m < SEQ) s = sacc[nt][r] * 0.125f + RBr[m];
        sacc[nt][r] = s;
        mx = fmaxf(mx, s);
      }
      mx = fmaxf(mx, __shfl_xor(mx, 1));
      mx = fmaxf(mx, __shfl_xor(mx, 2));
      mx = fmaxf(mx, __shfl_xor(mx, 4));
      mx = fmaxf(mx, __shfl_xor(mx, 8));
      float sum = 0.f;
#pragma unroll
      for (int nt = 0; nt < 13; nt++) {
        float e = __expf(sacc[nt][r] - mx);
        sacc[nt][r] = e;
        sum += e;
      }
      sum += __shfl_xor(sum, 1);
      sum += __shfl_xor(sum, 2);
      sum += __shfl_xor(sum, 4);
      sum += __shfl_xor(sum, 8);
      float inv = 1.f / sum;
      int prow = (quad * 4 + r) * PS;
#pragma unroll
      for (int nt = 0; nt < 13; nt++)
        Pw[prow + nt * 16 + c16] = f2bf(sacc[nt][r] * inv);
      Pw[prow + 208 + c16] = 0;   // zero pad cols 208..223
    }

    // O = P @ V  (A-frag from per-wave P, B-frag from shared Vt; same-wave RAW,
    // compiler inserts lgkmcnt)
    floatx4 oacc[4] = {};
#pragma unroll
    for (int ks = 0; ks < 7; ks++) {
      short8 a = *(const short8*)(Pw + c16 * PS + ks * 32 + quad * 8);
#pragma unroll
      for (int dt = 0; dt < 4; dt++) {
        short8 bb = *(const short8*)(Vt + (dt * 16 + c16) * VS + ks * 32 + quad * 8);
        oacc[dt] = mfma16(a, bb, oacc[dt]);
      }
    }
#pragma unroll
    for (int dt = 0; dt < 4; dt++) {
      int d = dt * 16 + c16;
#pragma unroll
      for (int r = 0; r < 4; r++) {
        int grow = q0 + quad * 4 + r;
        if (grow < SEQ)
          attn_out[((size_t)b * SEQ + grow) * CH + h * HD + d] = f2bf(oacc[dt][r]);
      }
    }
  }
}

// ---------------- proj GEMM: LDS-staged, out = AO @ Wp^T + b (fp32 out) ----------------
__global__ __launch_bounds__(256) void gemm_proj(const u16* __restrict__ A,
                                                 const u16* __restrict__ W,
                                                 const float* __restrict__ bias,
                                                 float* __restrict__ out) {
  __shared__ u16 As[128 * 32];
  __shared__ u16 Bs[128 * 32];
  int tid = threadIdx.x;
  int wave = tid >> 6, lane = tid & 63, quad = lane >> 4, c16 = lane & 15;
  int wm = wave >> 1, wn = wave & 1;
  int m0 = blockIdx.y * 128, n0 = blockIdx.x * 128;
  const u16* Ag = A + (size_t)(m0 + wave * 32 + (lane >> 2)) * CH + (lane & 3) * 8;
  const u16* Wg = W + (size_t)(n0 + wave * 32 + (lane >> 2)) * CH + (lane & 3) * 8;
  u16* AsW = As + wave * 32 * 32;
  u16* BsW = Bs + wave * 32 * 32;
  const u16* ArF = As + (wm * 64 + c16) * 32 + quad * 8;
  const u16* BrF = Bs + (wn * 64 + c16) * 32 + quad * 8;
  floatx4 acc[4][4] = {};
  for (int kk = 0; kk < CH; kk += 32) {
    __syncthreads();
    async16(Ag + kk, AsW);
    async16(Ag + kk + (size_t)16 * CH, AsW + 16 * 32);
    async16(Wg + kk, BsW);
    async16(Wg + kk + (size_t)16 * CH, BsW + 16 * 32);
    __syncthreads();
    short8 af[4], bfr[4];
#pragma unroll
    for (int i = 0; i < 4; i++) af[i] = *(const short8*)(ArF + i * 16 * 32);
#pragma unroll
    for (int j = 0; j < 4; j++) bfr[j] = *(const short8*)(BrF + j * 16 * 32);
#pragma unroll
    for (int i = 0; i < 4; i++)
#pragma unroll
      for (int j = 0; j < 4; j++) acc[i][j] = mfma16(af[i], bfr[j], acc[i][j]);
  }
#pragma unroll
  for (int j = 0; j < 4; j++) {
    int gcol = n0 + wn * 64 + j * 16 + c16;
    float bj = bias[gcol];
#pragma unroll
    for (int i = 0; i < 4; i++)
#pragma unroll
      for (int r = 0; r < 4; r++) {
        int grow = m0 + wm * 64 + i * 16 + quad * 4 + r;
        out[(size_t)grow * CH + gcol] = acc[i][j][r] + bj;
      }
  }
}

extern "C" void kernel_launch(void* const* d_in, const int* in_sizes, int n_in,
                              void* d_out, int out_size, void* d_ws, size_t ws_size,
                              hipStream_t stream) {
  const float* x      = (const float*)d_in[0];
  const float* qkv_w  = (const float*)d_in[1];
  const float* q_bias = (const float*)d_in[2];
  const float* v_bias = (const float*)d_in[3];
  const float* table  = (const float*)d_in[4];
  const float* proj_w = (const float*)d_in[5];
  const float* proj_b = (const float*)d_in[6];
  const int*   rel_ix = (const int*)d_in[7];
  float* out = (float*)d_out;

  char* ws = (char*)d_ws;
  size_t off = 0;
  u16* x_bf  = (u16*)(ws + off); off += (size_t)MROWS * CH * 2;
  u16* wq_bf = (u16*)(ws + off); off += (size_t)3 * CH * CH * 2;
  u16* wp_bf = (u16*)(ws + off); off += (size_t)CH * CH * 2;
  u16* q_buf = (u16*)(ws + off); off += (size_t)MROWS * CH * 2;
  u16* k_buf = (u16*)(ws + off); off += (size_t)MROWS * CH * 2;
  u16* v_buf = (u16*)(ws + off); off += (size_t)MROWS * CH * 2;
  u16* ao_bf = (u16*)(ws + off); off += (size_t)MROWS * CH * 2;
  float* relb = (float*)(ws + off);

  int n4x = MROWS * CH / 4;
  int n4q = 3 * CH * CH / 4;
  int n4p = CH * CH / 4;
  cvt_bf16<<<(n4x + 255) / 256, 256, 0, stream>>>((const float4*)x, (ushort4*)x_bf, n4x);
  cvt_bf16<<<(n4q + 255) / 256, 256, 0, stream>>>((const float4*)qkv_w, (ushort4*)wq_bf, n4q);
  cvt_bf16<<<(n4p + 255) / 256, 256, 0, stream>>>((const float4*)proj_w, (ushort4*)wp_bf, n4p);
  gather_relb<<<(SEQ * SEQ + 255) / 256, 256, 0, stream>>>(rel_ix, table, relb);
  gemm_qkv<<<dim3(18, 197), 256, 0, stream>>>(x_bf, wq_bf, q_bias, v_bias, q_buf, k_buf, v_buf);
  attn<<<dim3(NH, BATCH), 256, 0, stream>>>(q_buf, k_buf, v_buf, relb, ao_bf);
  gemm_proj<<<dim3(6, 197), 256, 0, stream>>>(ao_bf, wp_bf, proj_b, out);
}

// Round 4
// 430.421 us; speedup vs baseline: 2.0472x; 1.0258x over previous
//
#include <hip/hip_runtime.h>

typedef unsigned short u16;
typedef __attribute__((ext_vector_type(8))) short short8;
typedef __attribute__((ext_vector_type(8))) __bf16 bf16x8;
typedef __attribute__((ext_vector_type(4))) float floatx4;

#define BATCH 128
#define SEQ 197
#define CH 768
#define NH 12
#define HD 64
#define MROWS (BATCH * SEQ)   // 25216 = 197 * 128 exactly

__device__ __forceinline__ floatx4 mfma16(short8 a, short8 b, floatx4 c) {
  return __builtin_amdgcn_mfma_f32_16x16x32_bf16(
      __builtin_bit_cast(bf16x8, a), __builtin_bit_cast(bf16x8, b), c, 0, 0, 0);
}

__device__ __forceinline__ u16 f2bf(float f) {
  unsigned u = __builtin_bit_cast(unsigned, f);
  return (u16)((u + 0x7fffu + ((u >> 16) & 1u)) >> 16);
}

// async global->LDS, 16B per lane; LDS dest must be wave-uniform base (HW adds lane*16)
__device__ __forceinline__ void async16(const u16* g, u16* s) {
  __builtin_amdgcn_global_load_lds((const __attribute__((address_space(1))) void*)g,
                                   (__attribute__((address_space(3))) void*)s, 16, 0, 0);
}

// ---------------- fp32 -> bf16 convert (vectorized) ----------------
__global__ __launch_bounds__(256) void cvt_bf16(const float4* __restrict__ in,
                                                ushort4* __restrict__ out, int n4) {
  int i = blockIdx.x * 256 + threadIdx.x;
  if (i < n4) {
    float4 v = in[i];
    ushort4 o;
    o.x = f2bf(v.x); o.y = f2bf(v.y); o.z = f2bf(v.z); o.w = f2bf(v.w);
    out[i] = o;
  }
}

// ---------------- rel position bias gather: relb[h][n][m] ----------------
__global__ __launch_bounds__(256) void gather_relb(const int* __restrict__ idx,
                                                   const float* __restrict__ table,
                                                   float* __restrict__ relb) {
  int t = blockIdx.x * 256 + threadIdx.x;
  if (t < SEQ * SEQ) {
    int id = idx[t];
    const float* row = table + id * NH;
#pragma unroll
    for (int h = 0; h < NH; h++) relb[h * (SEQ * SEQ) + t] = row[h];
  }
}

// ---------------- QKV GEMM: 128x256 block tile, 64x128 wave tile ----------------
// grid (9, 197), block 256 = 4 waves. LDS-staged, BK=32.
__global__ __launch_bounds__(256, 2) void gemm_qkv(const u16* __restrict__ A,
                                                   const u16* __restrict__ W,
                                                   const float* __restrict__ qb,
                                                   const float* __restrict__ vb,
                                                   u16* __restrict__ q_buf,
                                                   u16* __restrict__ k_buf,
                                                   u16* __restrict__ v_buf) {
  __shared__ u16 As[128 * 32];   // 8 KB
  __shared__ u16 Bs[256 * 32];   // 16 KB
  int tid = threadIdx.x;
  int wave = tid >> 6, lane = tid & 63, quad = lane >> 4, c16 = lane & 15;
  int wm = wave >> 1, wn = wave & 1;
  int m0 = blockIdx.y * 128, n0 = blockIdx.x * 256;
  int lrow = lane >> 2, lcol = (lane & 3) * 8;
  // staging: wave stages 32 A-rows (2 instrs) + 64 B-rows (4 instrs), 16 rows each
  const u16* Ag0 = A + (size_t)(m0 + wave * 32 + lrow) * CH + lcol;
  const u16* Ag1 = Ag0 + (size_t)16 * CH;
  const u16* Bg0 = W + (size_t)(n0 + wave * 64 + lrow) * CH + lcol;
  const u16* Bg1 = Bg0 + (size_t)16 * CH;
  const u16* Bg2 = Bg0 + (size_t)32 * CH;
  const u16* Bg3 = Bg0 + (size_t)48 * CH;
  u16* AsW0 = As + (wave * 32) * 32;
  u16* AsW1 = As + (wave * 32 + 16) * 32;
  u16* BsW0 = Bs + (wave * 64) * 32;
  u16* BsW1 = Bs + (wave * 64 + 16) * 32;
  u16* BsW2 = Bs + (wave * 64 + 32) * 32;
  u16* BsW3 = Bs + (wave * 64 + 48) * 32;
  const u16* ArF = As + (wm * 64 + c16) * 32 + quad * 8;
  const u16* BrF = Bs + (wn * 128 + c16) * 32 + quad * 8;
  floatx4 acc[4][8] = {};
  for (int kk = 0; kk < CH; kk += 32) {
    __syncthreads();
    async16(Ag0 + kk, AsW0);
    async16(Ag1 + kk, AsW1);
    async16(Bg0 + kk, BsW0);
    async16(Bg1 + kk, BsW1);
    async16(Bg2 + kk, BsW2);
    async16(Bg3 + kk, BsW3);
    __syncthreads();
    short8 af[4], bfr[8];
#pragma unroll
    for (int i = 0; i < 4; i++) af[i] = *(const short8*)(ArF + i * 16 * 32);
#pragma unroll
    for (int j = 0; j < 8; j++) bfr[j] = *(const short8*)(BrF + j * 16 * 32);
#pragma unroll
    for (int i = 0; i < 4; i++)
#pragma unroll
      for (int j = 0; j < 8; j++) acc[i][j] = mfma16(af[i], bfr[j], acc[i][j]);
  }
#pragma unroll
  for (int j = 0; j < 8; j++) {
    int gcol = n0 + wn * 128 + j * 16 + c16;  // 0..2303
    int t = gcol / CH;                         // 0=q 1=k 2=v (uniform per 16-col group)
    int rem = gcol - t * CH;                   // h*64+d
    int h = rem >> 6, d = rem & 63;
    float badd = (t == 0) ? qb[rem] : (t == 2 ? vb[rem] : 0.0f);
    u16* dst = (t == 0) ? q_buf : (t == 1 ? k_buf : v_buf);
#pragma unroll
    for (int i = 0; i < 4; i++) {
#pragma unroll
      for (int r = 0; r < 4; r++) {
        int grow = m0 + wm * 64 + i * 16 + quad * 4 + r;  // 0..25215
        int bb = grow / SEQ;
        int n = grow - bb * SEQ;
        dst[(((size_t)bb * NH + h) * SEQ + n) * HD + d] = f2bf(acc[i][j][r] + badd);
      }
    }
  }
}

// ---------------- attention: one block per (h, b), register softmax ----------------
#define PS 232
#define VS 264

__global__ __launch_bounds__(256, 2) void attn(const u16* __restrict__ q_buf,
                                               const u16* __restrict__ k_buf,
                                               const u16* __restrict__ v_buf,
                                               const float* __restrict__ relb,
                                               u16* __restrict__ attn_out) {
  __shared__ u16 Vt[64 * VS];        // 33792 B : V transposed [d][m], zero-padded m>=197
  __shared__ u16 P[4 * 16 * PS];     // 29696 B : per-wave P tiles

  int h = blockIdx.x, b = blockIdx.y;
  int tid = threadIdx.x, wave = tid >> 6, lane = tid & 63, quad = lane >> 4, c16 = lane & 15;
  size_t bh = (size_t)b * NH + h;
  const u16* Q = q_buf + bh * SEQ * HD;
  const u16* Kp = k_buf + bh * SEQ * HD;
  const u16* Vp = v_buf + bh * SEQ * HD;
  const float* RB = relb + (size_t)h * (SEQ * SEQ);

  {
    int mrow = tid >> 3, dbase = (tid & 7) * 8;
#pragma unroll
    for (int i = 0; i < 7; i++) {
      int m = mrow + 32 * i;
      if (m < SEQ) {
        ushort4 v0 = *(const ushort4*)(Vp + m * HD + dbase);
        ushort4 v1 = *(const ushort4*)(Vp + m * HD + dbase + 4);
        Vt[(dbase + 0) * VS + m] = v0.x;
        Vt[(dbase + 1) * VS + m] = v0.y;
        Vt[(dbase + 2) * VS + m] = v0.z;
        Vt[(dbase + 3) * VS + m] = v0.w;
        Vt[(dbase + 4) * VS + m] = v1.x;
        Vt[(dbase + 5) * VS + m] = v1.y;
        Vt[(dbase + 6) * VS + m] = v1.z;
        Vt[(dbase + 7) * VS + m] = v1.w;
      } else {
#pragma unroll
        for (int dd = 0; dd < 8; dd++) Vt[(dbase + dd) * VS + m] = 0;
      }
    }
  }
  __syncthreads();   // the only barrier

  u16* Pw = P + wave * 16 * PS;
  for (int rt = wave; rt < 13; rt += 4) {
    int q0 = rt * 16;
    int qr = min(q0 + c16, SEQ - 1);
    short8 qa0 = *(const short8*)(Q + qr * HD + quad * 8);
    short8 qa1 = *(const short8*)(Q + qr * HD + 32 + quad * 8);

    floatx4 sacc[13];
#pragma unroll
    for (int nt = 0; nt < 13; nt++) {
      int mc = min(nt * 16 + c16, SEQ - 1);
      floatx4 a = {0.f, 0.f, 0.f, 0.f};
      a = mfma16(qa0, *(const short8*)(Kp + mc * HD + quad * 8), a);
      a = mfma16(qa1, *(const short8*)(Kp + mc * HD + 32 + quad * 8), a);
      sacc[nt] = a;
    }

#pragma unroll
    for (int r = 0; r < 4; r++) {
      int rq = min(q0 + quad * 4 + r, SEQ - 1);
      const float* RBr = RB + (size_t)rq * SEQ;
      float mx = -1e30f;
#pragma unroll
      for (int nt = 0; nt < 13; nt++) {
        int m = nt * 16 + c16;
        float s = -1e30f;
        if (m < SEQ) s = sacc[nt][r] * 0.125f + RBr[m];
        sacc[nt][r] = s;
        mx = fmaxf(mx, s);
      }
      mx = fmaxf(mx, __shfl_xor(mx, 1));
      mx = fmaxf(mx, __shfl_xor(mx, 2));
      mx = fmaxf(mx, __shfl_xor(mx, 4));
      mx = fmaxf(mx, __shfl_xor(mx, 8));
      float sum = 0.f;
#pragma unroll
      for (int nt = 0; nt < 13; nt++) {
        float e = __expf(sacc[nt][r] - mx);
        sacc[nt][r] = e;
        sum += e;
      }
      sum += __shfl_xor(sum, 1);
      sum += __shfl_xor(sum, 2);
      sum += __shfl_xor(sum, 4);
      sum += __shfl_xor(sum, 8);
      float inv = 1.f / sum;
      int prow = (quad * 4 + r) * PS;
#pragma unroll
      for (int nt = 0; nt < 13; nt++)
        Pw[prow + nt * 16 + c16] = f2bf(sacc[nt][r] * inv);
      Pw[prow + 208 + c16] = 0;
    }

    floatx4 oacc[4] = {};
#pragma unroll
    for (int ks = 0; ks < 7; ks++) {
      short8 a = *(const short8*)(Pw + c16 * PS + ks * 32 + quad * 8);
#pragma unroll
      for (int dt = 0; dt < 4; dt++) {
        short8 bb = *(const short8*)(Vt + (dt * 16 + c16) * VS + ks * 32 + quad * 8);
        oacc[dt] = mfma16(a, bb, oacc[dt]);
      }
    }
#pragma unroll
    for (int dt = 0; dt < 4; dt++) {
      int d = dt * 16 + c16;
#pragma unroll
      for (int r = 0; r < 4; r++) {
        int grow = q0 + quad * 4 + r;
        if (grow < SEQ)
          attn_out[((size_t)b * SEQ + grow) * CH + h * HD + d] = f2bf(oacc[dt][r]);
      }
    }
  }
}

// ---------------- proj GEMM: 128x256 block tile, 64x128 wave tile, fp32 out ----------------
__global__ __launch_bounds__(256, 2) void gemm_proj(const u16* __restrict__ A,
                                                    const u16* __restrict__ W,
                                                    const float* __restrict__ bias,
                                                    float* __restrict__ out) {
  __shared__ u16 As[128 * 32];
  __shared__ u16 Bs[256 * 32];
  int tid = threadIdx.x;
  int wave = tid >> 6, lane = tid & 63, quad = lane >> 4, c16 = lane & 15;
  int wm = wave >> 1, wn = wave & 1;
  int m0 = blockIdx.y * 128, n0 = blockIdx.x * 256;
  int lrow = lane >> 2, lcol = (lane & 3) * 8;
  const u16* Ag0 = A + (size_t)(m0 + wave * 32 + lrow) * CH + lcol;
  const u16* Ag1 = Ag0 + (size_t)16 * CH;
  const u16* Bg0 = W + (size_t)(n0 + wave * 64 + lrow) * CH + lcol;
  const u16* Bg1 = Bg0 + (size_t)16 * CH;
  const u16* Bg2 = Bg0 + (size_t)32 * CH;
  const u16* Bg3 = Bg0 + (size_t)48 * CH;
  u16* AsW0 = As + (wave * 32) * 32;
  u16* AsW1 = As + (wave * 32 + 16) * 32;
  u16* BsW0 = Bs + (wave * 64) * 32;
  u16* BsW1 = Bs + (wave * 64 + 16) * 32;
  u16* BsW2 = Bs + (wave * 64 + 32) * 32;
  u16* BsW3 = Bs + (wave * 64 + 48) * 32;
  const u16* ArF = As + (wm * 64 + c16) * 32 + quad * 8;
  const u16* BrF = Bs + (wn * 128 + c16) * 32 + quad * 8;
  floatx4 acc[4][8] = {};
  for (int kk = 0; kk < CH; kk += 32) {
    __syncthreads();
    async16(Ag0 + kk, AsW0);
    async16(Ag1 + kk, AsW1);
    async16(Bg0 + kk, BsW0);
    async16(Bg1 + kk, BsW1);
    async16(Bg2 + kk, BsW2);
    async16(Bg3 + kk, BsW3);
    __syncthreads();
    short8 af[4], bfr[8];
#pragma unroll
    for (int i = 0; i < 4; i++) af[i] = *(const short8*)(ArF + i * 16 * 32);
#pragma unroll
    for (int j = 0; j < 8; j++) bfr[j] = *(const short8*)(BrF + j * 16 * 32);
#pragma unroll
    for (int i = 0; i < 4; i++)
#pragma unroll
      for (int j = 0; j < 8; j++) acc[i][j] = mfma16(af[i], bfr[j], acc[i][j]);
  }
#pragma unroll
  for (int j = 0; j < 8; j++) {
    int gcol = n0 + wn * 128 + j * 16 + c16;
    float bj = bias[gcol];
#pragma unroll
    for (int i = 0; i < 4; i++)
#pragma unroll
      for (int r = 0; r < 4; r++) {
        int grow = m0 + wm * 64 + i * 16 + quad * 4 + r;
        out[(size_t)grow * CH + gcol] = acc[i][j][r] + bj;
      }
  }
}

extern "C" void kernel_launch(void* const* d_in, const int* in_sizes, int n_in,
                              void* d_out, int out_size, void* d_ws, size_t ws_size,
                              hipStream_t stream) {
  const float* x      = (const float*)d_in[0];
  const float* qkv_w  = (const float*)d_in[1];
  const float* q_bias = (const float*)d_in[2];
  const float* v_bias = (const float*)d_in[3];
  const float* table  = (const float*)d_in[4];
  const float* proj_w = (const float*)d_in[5];
  const float* proj_b = (const float*)d_in[6];
  const int*   rel_ix = (const int*)d_in[7];
  float* out = (float*)d_out;

  char* ws = (char*)d_ws;
  size_t off = 0;
  u16* x_bf  = (u16*)(ws + off); off += (size_t)MROWS * CH * 2;
  u16* wq_bf = (u16*)(ws + off); off += (size_t)3 * CH * CH * 2;
  u16* wp_bf = (u16*)(ws + off); off += (size_t)CH * CH * 2;
  u16* q_buf = (u16*)(ws + off); off += (size_t)MROWS * CH * 2;
  u16* k_buf = (u16*)(ws + off); off += (size_t)MROWS * CH * 2;
  u16* v_buf = (u16*)(ws + off); off += (size_t)MROWS * CH * 2;
  u16* ao_bf = (u16*)(ws + off); off += (size_t)MROWS * CH * 2;
  float* relb = (float*)(ws + off);

  int n4x = MROWS * CH / 4;
  int n4q = 3 * CH * CH / 4;
  int n4p = CH * CH / 4;
  cvt_bf16<<<(n4x + 255) / 256, 256, 0, stream>>>((const float4*)x, (ushort4*)x_bf, n4x);
  cvt_bf16<<<(n4q + 255) / 256, 256, 0, stream>>>((const float4*)qkv_w, (ushort4*)wq_bf, n4q);
  cvt_bf16<<<(n4p + 255) / 256, 256, 0, stream>>>((const float4*)proj_w, (ushort4*)wp_bf, n4p);
  gather_relb<<<(SEQ * SEQ + 255) / 256, 256, 0, stream>>>(rel_ix, table, relb);
  gemm_qkv<<<dim3(9, 197), 256, 0, stream>>>(x_bf, wq_bf, q_bias, v_bias, q_buf, k_buf, v_buf);
  attn<<<dim3(NH, BATCH), 256, 0, stream>>>(q_buf, k_buf, v_buf, relb, ao_bf);
  gemm_proj<<<dim3(3, 197), 256, 0, stream>>>(ao_bf, wp_bf, proj_b, out);
}

// Round 5
// 418.851 us; speedup vs baseline: 2.1038x; 1.0276x over previous
//
#include <hip/hip_runtime.h>

typedef unsigned short u16;
typedef __attribute__((ext_vector_type(8))) short short8;
typedef __attribute__((ext_vector_type(8))) __bf16 bf16x8;
typedef __attribute__((ext_vector_type(4))) float floatx4;

#define BATCH 128
#define SEQ 197
#define CH 768
#define NH 12
#define HD 64
#define MROWS (BATCH * SEQ)   // 25216 = 197 * 128 exactly

__device__ __forceinline__ floatx4 mfma16(short8 a, short8 b, floatx4 c) {
  return __builtin_amdgcn_mfma_f32_16x16x32_bf16(
      __builtin_bit_cast(bf16x8, a), __builtin_bit_cast(bf16x8, b), c, 0, 0, 0);
}

__device__ __forceinline__ u16 f2bf(float f) {
  unsigned u = __builtin_bit_cast(unsigned, f);
  return (u16)((u + 0x7fffu + ((u >> 16) & 1u)) >> 16);
}

// async global->LDS, 16B per lane; LDS dest is wave-uniform base + lane*16
__device__ __forceinline__ void async16(const u16* g, u16* s) {
  __builtin_amdgcn_global_load_lds((const __attribute__((address_space(1))) void*)g,
                                   (__attribute__((address_space(3))) void*)s, 16, 0, 0);
}

// ---------------- fused preprocessing: 3x fp32->bf16 + relb gather ----------------
__global__ __launch_bounds__(256) void preproc(const float4* __restrict__ x, ushort4* __restrict__ xo, int n0,
                                               const float4* __restrict__ w1, ushort4* __restrict__ w1o, int n1,
                                               const float4* __restrict__ w2, ushort4* __restrict__ w2o, int n2,
                                               const int* __restrict__ idx, const float* __restrict__ table,
                                               float* __restrict__ relb) {
  int i = blockIdx.x * 256 + threadIdx.x;
  const float4* in; ushort4* out; int j;
  if (i < n0) { in = x; out = xo; j = i; }
  else if (i < n0 + n1) { in = w1; out = w1o; j = i - n0; }
  else if (i < n0 + n1 + n2) { in = w2; out = w2o; j = i - n0 - n1; }
  else {
    int t = i - (n0 + n1 + n2);
    if (t < SEQ * SEQ) {
      int id = idx[t];
      const float* row = table + id * NH;
#pragma unroll
      for (int h = 0; h < NH; h++) relb[h * (SEQ * SEQ) + t] = row[h];
    }
    return;
  }
  float4 v = in[j];
  ushort4 o;
  o.x = f2bf(v.x); o.y = f2bf(v.y); o.z = f2bf(v.z); o.w = f2bf(v.w);
  out[j] = o;
}

// ---------------- QKV GEMM: 128x256 tile, XOR-swizzled LDS (conflict-free) ----------------
// grid (9, 197), block 256 = 4 waves. BK=32.
// LDS row R, physical slot s (4 slots x 8 u16) holds global col-group s ^ ((R>>1)&3).
__global__ __launch_bounds__(256, 2) void gemm_qkv(const u16* __restrict__ A,
                                                   const u16* __restrict__ W,
                                                   const float* __restrict__ qb,
                                                   const float* __restrict__ vb,
                                                   u16* __restrict__ q_buf,
                                                   u16* __restrict__ k_buf,
                                                   u16* __restrict__ v_buf) {
  __shared__ u16 As[128 * 32];   // 8 KB
  __shared__ u16 Bs[256 * 32];   // 16 KB
  int tid = threadIdx.x;
  int wave = tid >> 6, lane = tid & 63, quad = lane >> 4, c16 = lane & 15;
  int wm = wave >> 1, wn = wave & 1;
  int m0 = blockIdx.y * 128, n0 = blockIdx.x * 256;
  int lrow = lane >> 2;
  int lcol = (((lane & 3) ^ ((lane >> 3) & 3))) * 8;   // swizzled source col-group
  const u16* Ag0 = A + (size_t)(m0 + wave * 32 + lrow) * CH + lcol;
  const u16* Ag1 = Ag0 + (size_t)16 * CH;
  const u16* Bg0 = W + (size_t)(n0 + wave * 64 + lrow) * CH + lcol;
  const u16* Bg1 = Bg0 + (size_t)16 * CH;
  const u16* Bg2 = Bg0 + (size_t)32 * CH;
  const u16* Bg3 = Bg0 + (size_t)48 * CH;
  u16* AsW0 = As + (wave * 32) * 32;
  u16* AsW1 = As + (wave * 32 + 16) * 32;
  u16* BsW0 = Bs + (wave * 64) * 32;
  u16* BsW1 = Bs + (wave * 64 + 16) * 32;
  u16* BsW2 = Bs + (wave * 64 + 32) * 32;
  u16* BsW3 = Bs + (wave * 64 + 48) * 32;
  int fsl = (quad ^ ((c16 >> 1) & 3)) * 8;             // swizzled fragment slot
  const u16* ArF = As + (wm * 64 + c16) * 32 + fsl;
  const u16* BrF = Bs + (wn * 128 + c16) * 32 + fsl;
  floatx4 acc[4][8] = {};
  for (int kk = 0; kk < CH; kk += 32) {
    __syncthreads();
    async16(Ag0 + kk, AsW0);
    async16(Ag1 + kk, AsW1);
    async16(Bg0 + kk, BsW0);
    async16(Bg1 + kk, BsW1);
    async16(Bg2 + kk, BsW2);
    async16(Bg3 + kk, BsW3);
    __syncthreads();
    short8 af[4], bfr[8];
#pragma unroll
    for (int i = 0; i < 4; i++) af[i] = *(const short8*)(ArF + i * 16 * 32);
#pragma unroll
    for (int j = 0; j < 8; j++) bfr[j] = *(const short8*)(BrF + j * 16 * 32);
#pragma unroll
    for (int i = 0; i < 4; i++)
#pragma unroll
      for (int j = 0; j < 8; j++) acc[i][j] = mfma16(af[i], bfr[j], acc[i][j]);
  }
#pragma unroll
  for (int j = 0; j < 8; j++) {
    int gcol = n0 + wn * 128 + j * 16 + c16;  // 0..2303
    int t = gcol / CH;                         // 0=q 1=k 2=v
    int rem = gcol - t * CH;                   // h*64+d
    int h = rem >> 6, d = rem & 63;
    float badd = (t == 0) ? qb[rem] : (t == 2 ? vb[rem] : 0.0f);
    u16* dst = (t == 0) ? q_buf : (t == 1 ? k_buf : v_buf);
#pragma unroll
    for (int i = 0; i < 4; i++) {
#pragma unroll
      for (int r = 0; r < 4; r++) {
        int grow = m0 + wm * 64 + i * 16 + quad * 4 + r;
        int bb = grow / SEQ;
        int n = grow - bb * SEQ;
        dst[(((size_t)bb * NH + h) * SEQ + n) * HD + d] = f2bf(acc[i][j][r] + badd);
      }
    }
  }
}

// ---------------- attention: one block per (h, b), register softmax ----------------
#define PS 232
#define VS 264

__global__ __launch_bounds__(256, 2) void attn(const u16* __restrict__ q_buf,
                                               const u16* __restrict__ k_buf,
                                               const u16* __restrict__ v_buf,
                                               const float* __restrict__ relb,
                                               u16* __restrict__ attn_out) {
  __shared__ u16 Vt[64 * VS];
  __shared__ u16 P[4 * 16 * PS];

  int h = blockIdx.x, b = blockIdx.y;
  int tid = threadIdx.x, wave = tid >> 6, lane = tid & 63, quad = lane >> 4, c16 = lane & 15;
  size_t bh = (size_t)b * NH + h;
  const u16* Q = q_buf + bh * SEQ * HD;
  const u16* Kp = k_buf + bh * SEQ * HD;
  const u16* Vp = v_buf + bh * SEQ * HD;
  const float* RB = relb + (size_t)h * (SEQ * SEQ);

  {
    int mrow = tid >> 3, dbase = (tid & 7) * 8;
#pragma unroll
    for (int i = 0; i < 7; i++) {
      int m = mrow + 32 * i;
      if (m < SEQ) {
        ushort4 v0 = *(const ushort4*)(Vp + m * HD + dbase);
        ushort4 v1 = *(const ushort4*)(Vp + m * HD + dbase + 4);
        Vt[(dbase + 0) * VS + m] = v0.x;
        Vt[(dbase + 1) * VS + m] = v0.y;
        Vt[(dbase + 2) * VS + m] = v0.z;
        Vt[(dbase + 3) * VS + m] = v0.w;
        Vt[(dbase + 4) * VS + m] = v1.x;
        Vt[(dbase + 5) * VS + m] = v1.y;
        Vt[(dbase + 6) * VS + m] = v1.z;
        Vt[(dbase + 7) * VS + m] = v1.w;
      } else {
#pragma unroll
        for (int dd = 0; dd < 8; dd++) Vt[(dbase + dd) * VS + m] = 0;
      }
    }
  }
  __syncthreads();

  u16* Pw = P + wave * 16 * PS;
  for (int rt = wave; rt < 13; rt += 4) {
    int q0 = rt * 16;
    int qr = min(q0 + c16, SEQ - 1);
    short8 qa0 = *(const short8*)(Q + qr * HD + quad * 8);
    short8 qa1 = *(const short8*)(Q + qr * HD + 32 + quad * 8);

    floatx4 sacc[13];
#pragma unroll
    for (int nt = 0; nt < 13; nt++) {
      int mc = min(nt * 16 + c16, SEQ - 1);
      floatx4 a = {0.f, 0.f, 0.f, 0.f};
      a = mfma16(qa0, *(const short8*)(Kp + mc * HD + quad * 8), a);
      a = mfma16(qa1, *(const short8*)(Kp + mc * HD + 32 + quad * 8), a);
      sacc[nt] = a;
    }

#pragma unroll
    for (int r = 0; r < 4; r++) {
      int rq = min(q0 + quad * 4 + r, SEQ - 1);
      const float* RBr = RB + (size_t)rq * SEQ;
      float mx = -1e30f;
#pragma unroll
      for (int nt = 0; nt < 13; nt++) {
        int m = nt * 16 + c16;
        float s = -1e30f;
        if (m < SEQ) s = sacc[nt][r] * 0.125f + RBr[m];
        sacc[nt][r] = s;
        mx = fmaxf(mx, s);
      }
      mx = fmaxf(mx, __shfl_xor(mx, 1));
      mx = fmaxf(mx, __shfl_xor(mx, 2));
      mx = fmaxf(mx, __shfl_xor(mx, 4));
      mx = fmaxf(mx, __shfl_xor(mx, 8));
      float sum = 0.f;
#pragma unroll
      for (int nt = 0; nt < 13; nt++) {
        float e = __expf(sacc[nt][r] - mx);
        sacc[nt][r] = e;
        sum += e;
      }
      sum += __shfl_xor(sum, 1);
      sum += __shfl_xor(sum, 2);
      sum += __shfl_xor(sum, 4);
      sum += __shfl_xor(sum, 8);
      float inv = 1.f / sum;
      int prow = (quad * 4 + r) * PS;
#pragma unroll
      for (int nt = 0; nt < 13; nt++)
        Pw[prow + nt * 16 + c16] = f2bf(sacc[nt][r] * inv);
      Pw[prow + 208 + c16] = 0;
    }

    floatx4 oacc[4] = {};
#pragma unroll
    for (int ks = 0; ks < 7; ks++) {
      short8 a = *(const short8*)(Pw + c16 * PS + ks * 32 + quad * 8);
#pragma unroll
      for (int dt = 0; dt < 4; dt++) {
        short8 bb = *(const short8*)(Vt + (dt * 16 + c16) * VS + ks * 32 + quad * 8);
        oacc[dt] = mfma16(a, bb, oacc[dt]);
      }
    }
#pragma unroll
    for (int dt = 0; dt < 4; dt++) {
      int d = dt * 16 + c16;
#pragma unroll
      for (int r = 0; r < 4; r++) {
        int grow = q0 + quad * 4 + r;
        if (grow < SEQ)
          attn_out[((size_t)b * SEQ + grow) * CH + h * HD + d] = f2bf(oacc[dt][r]);
      }
    }
  }
}

// ---------------- proj GEMM: 128x256 tile, XOR-swizzled LDS, fp32 out ----------------
__global__ __launch_bounds__(256, 2) void gemm_proj(const u16* __restrict__ A,
                                                    const u16* __restrict__ W,
                                                    const float* __restrict__ bias,
                                                    float* __restrict__ out) {
  __shared__ u16 As[128 * 32];
  __shared__ u16 Bs[256 * 32];
  int tid = threadIdx.x;
  int wave = tid >> 6, lane = tid & 63, quad = lane >> 4, c16 = lane & 15;
  int wm = wave >> 1, wn = wave & 1;
  int m0 = blockIdx.y * 128, n0 = blockIdx.x * 256;
  int lrow = lane >> 2;
  int lcol = (((lane & 3) ^ ((lane >> 3) & 3))) * 8;
  const u16* Ag0 = A + (size_t)(m0 + wave * 32 + lrow) * CH + lcol;
  const u16* Ag1 = Ag0 + (size_t)16 * CH;
  const u16* Bg0 = W + (size_t)(n0 + wave * 64 + lrow) * CH + lcol;
  const u16* Bg1 = Bg0 + (size_t)16 * CH;
  const u16* Bg2 = Bg0 + (size_t)32 * CH;
  const u16* Bg3 = Bg0 + (size_t)48 * CH;
  u16* AsW0 = As + (wave * 32) * 32;
  u16* AsW1 = As + (wave * 32 + 16) * 32;
  u16* BsW0 = Bs + (wave * 64) * 32;
  u16* BsW1 = Bs + (wave * 64 + 16) * 32;
  u16* BsW2 = Bs + (wave * 64 + 32) * 32;
  u16* BsW3 = Bs + (wave * 64 + 48) * 32;
  int fsl = (quad ^ ((c16 >> 1) & 3)) * 8;
  const u16* ArF = As + (wm * 64 + c16) * 32 + fsl;
  const u16* BrF = Bs + (wn * 128 + c16) * 32 + fsl;
  floatx4 acc[4][8] = {};
  for (int kk = 0; kk < CH; kk += 32) {
    __syncthreads();
    async16(Ag0 + kk, AsW0);
    async16(Ag1 + kk, AsW1);
    async16(Bg0 + kk, BsW0);
    async16(Bg1 + kk, BsW1);
    async16(Bg2 + kk, BsW2);
    async16(Bg3 + kk, BsW3);
    __syncthreads();
    short8 af[4], bfr[8];
#pragma unroll
    for (int i = 0; i < 4; i++) af[i] = *(const short8*)(ArF + i * 16 * 32);
#pragma unroll
    for (int j = 0; j < 8; j++) bfr[j] = *(const short8*)(BrF + j * 16 * 32);
#pragma unroll
    for (int i = 0; i < 4; i++)
#pragma unroll
      for (int j = 0; j < 8; j++) acc[i][j] = mfma16(af[i], bfr[j], acc[i][j]);
  }
#pragma unroll
  for (int j = 0; j < 8; j++) {
    int gcol = n0 + wn * 128 + j * 16 + c16;
    float bj = bias[gcol];
#pragma unroll
    for (int i = 0; i < 4; i++)
#pragma unroll
      for (int r = 0; r < 4; r++) {
        int grow = m0 + wm * 64 + i * 16 + quad * 4 + r;
        out[(size_t)grow * CH + gcol] = acc[i][j][r] + bj;
      }
  }
}

extern "C" void kernel_launch(void* const* d_in, const int* in_sizes, int n_in,
                              void* d_out, int out_size, void* d_ws, size_t ws_size,
                              hipStream_t stream) {
  const float* x      = (const float*)d_in[0];
  const float* qkv_w  = (const float*)d_in[1];
  const float* q_bias = (const float*)d_in[2];
  const float* v_bias = (const float*)d_in[3];
  const float* table  = (const float*)d_in[4];
  const float* proj_w = (const float*)d_in[5];
  const float* proj_b = (const float*)d_in[6];
  const int*   rel_ix = (const int*)d_in[7];
  float* out = (float*)d_out;

  char* ws = (char*)d_ws;
  size_t off = 0;
  u16* x_bf  = (u16*)(ws + off); off += (size_t)MROWS * CH * 2;
  u16* wq_bf = (u16*)(ws + off); off += (size_t)3 * CH * CH * 2;
  u16* wp_bf = (u16*)(ws + off); off += (size_t)CH * CH * 2;
  u16* q_buf = (u16*)(ws + off); off += (size_t)MROWS * CH * 2;
  u16* k_buf = (u16*)(ws + off); off += (size_t)MROWS * CH * 2;
  u16* v_buf = (u16*)(ws + off); off += (size_t)MROWS * CH * 2;
  u16* ao_bf = (u16*)(ws + off); off += (size_t)MROWS * CH * 2;
  float* relb = (float*)(ws + off);

  int n0 = MROWS * CH / 4;
  int n1 = 3 * CH * CH / 4;
  int n2 = CH * CH / 4;
  int ntot = n0 + n1 + n2 + SEQ * SEQ;
  preproc<<<(ntot + 255) / 256, 256, 0, stream>>>(
      (const float4*)x, (ushort4*)x_bf, n0,
      (const float4*)qkv_w, (ushort4*)wq_bf, n1,
      (const float4*)proj_w, (ushort4*)wp_bf, n2,
      rel_ix, table, relb);
  gemm_qkv<<<dim3(9, 197), 256, 0, stream>>>(x_bf, wq_bf, q_bias, v_bias, q_buf, k_buf, v_buf);
  attn<<<dim3(NH, BATCH), 256, 0, stream>>>(q_buf, k_buf, v_buf, relb, ao_bf);
  gemm_proj<<<dim3(3, 197), 256, 0, stream>>>(ao_bf, wp_bf, proj_b, out);
}